// Round 3
// baseline (2498.937 us; speedup 1.0000x reference)
//
#include <hip/hip_runtime.h>

typedef unsigned short u16;
typedef __bf16 bf16x8 __attribute__((ext_vector_type(8)));
typedef float f32x4 __attribute__((ext_vector_type(4)));

#define T_TOK 200704   // 4*224*224
#define NTOK 49

__device__ __forceinline__ u16 f2bf(float f) {
    union { float f; unsigned u; } v; v.f = f;
    return (u16)((v.u + 0x7FFFu + ((v.u >> 16) & 1u)) >> 16);
}
__device__ __forceinline__ bf16x8 zfrag() {
    bf16x8 z;
#pragma unroll
    for (int i = 0; i < 8; ++i) z[i] = (__bf16)0.0f;
    return z;
}

// ---------------- transpose fp32 (K x N) -> bf16 (N x K) ----------------
__global__ void k_transpose(const float* __restrict__ in, u16* __restrict__ out, int K, int N) {
    int idx = blockIdx.x * blockDim.x + threadIdx.x;
    if (idx >= K * N) return;
    int k = idx / N, n = idx - k * N;
    out[n * K + k] = f2bf(in[idx]);
}

// GEMM: out(49 x 64-strip) = A(49x256) @ W(256x256), W transposed bf16 WT[n][k].
// A in LDS row-major [49][256] bf16.
__device__ __forceinline__ void gemm49(const u16* A, const u16* WT,
                                       int nb, int lane, f32x4 acc[4][4]) {
    const int ar = lane & 15;
    const int kg = (lane >> 4) * 8;
    const bf16x8 z = zfrag();
    for (int k0 = 0; k0 < 256; k0 += 32) {
        bf16x8 a[4], bb[4];
#pragma unroll
        for (int mt = 0; mt < 4; ++mt) {
            int row = mt * 16 + ar;
            a[mt] = (row < NTOK) ? *(const bf16x8*)(A + row * 256 + k0 + kg) : z;
        }
#pragma unroll
        for (int nt = 0; nt < 4; ++nt) {
            int col = nb + nt * 16 + ar;
            bb[nt] = *(const bf16x8*)(WT + col * 256 + k0 + kg);
        }
#pragma unroll
        for (int mt = 0; mt < 4; ++mt)
#pragma unroll
            for (int nt = 0; nt < 4; ++nt)
                acc[mt][nt] = __builtin_amdgcn_mfma_f32_16x16x32_bf16(a[mt], bb[nt], acc[mt][nt], 0, 0, 0);
    }
}

// ---------------- fused windowed cross-attention block ----------------
// grid = 4096 (B*nW), block = 256 (4 waves). fp32 global I/O.
// dst = src + reverse(proj(attn(LN(src) windows, enc windows)))
// src may alias dst (block 2 in-place): windows partition the token set, so each
// block touches only its own tokens.
__global__ __launch_bounds__(256) void k_win_attn(
    const float* src, float* dst, const float* __restrict__ enc,
    const float* __restrict__ lng, const float* __restrict__ lnb,
    const u16* __restrict__ wqT, const u16* __restrict__ wkT,
    const u16* __restrict__ wvT, const u16* __restrict__ wpT,
    const float* __restrict__ bq, const float* __restrict__ bk,
    const float* __restrict__ bv, const float* __restrict__ bp,
    const float* __restrict__ rpb, int shift)
{
    __shared__ __align__(16) char smem[133632];
    u16* yL   = (u16*)(smem);            // [49][256] bf16 (aliased later by S)
    u16* encL = (u16*)(smem + 25088);    // [49][256] bf16 (aliased later by S)
    u16* qL   = (u16*)(smem + 50176);    // [49][256] ; later P[4][49][64]
    u16* kL   = (u16*)(smem + 75264);    // [49][256] ; later O[49][256]
    u16* vT   = (u16*)(smem + 100352);   // [256][64] v transposed (channel-major)
    int* t_idx = (int*)(smem + 133120);  // [49]
    int* label = (int*)(smem + 133316);  // [49]
    float* S  = (float*)(smem);          // [4][49][49] fp32 (aliases yL/encL)
    u16* P    = qL;                      // [4][49][64] bf16 probs
    u16* O    = kL;                      // [49][256] attn out (heads concat)

    const int tid = threadIdx.x, lane = tid & 63, wave = tid >> 6;
    const int wi = blockIdx.x;
    const int b  = wi >> 10;
    const int wl = wi & 1023;
    const int wh = wl >> 5, wwi = wl & 31;

    if (tid < NTOK) {
        int yi = tid / 7, xi = tid - yi * 7;
        int h = wh * 7 + yi + shift; if (h >= 224) h -= 224;
        int w = wwi * 7 + xi + shift; if (w >= 224) w -= 224;
        t_idx[tid] = (b * 224 + h) * 224 + w;
        int hp = wh * 7 + yi, wp = wwi * 7 + xi;   // rolled-frame coords
        int rh = (hp < 217) ? 0 : ((hp < 221) ? 1 : 2);
        int rw = (wp < 217) ? 0 : ((wp < 221) ? 1 : 2);
        label[tid] = rh * 3 + rw;
    }
    __syncthreads();

    // ---- phase 1: load enc window (fp32->bf16); LN(src) -> yL bf16 ----
    for (int idx = tid; idx < NTOK * 64; idx += 256) {
        int r = idx >> 6, c4 = (idx & 63) << 2;
        const float4 v = *(const float4*)(enc + (size_t)t_idx[r] * 256 + c4);
        u16* p = encL + r * 256 + c4;
        p[0] = f2bf(v.x); p[1] = f2bf(v.y); p[2] = f2bf(v.z); p[3] = f2bf(v.w);
    }
    for (int r = wave; r < NTOK; r += 4) {
        const float4 xv = *(const float4*)(src + (size_t)t_idx[r] * 256 + lane * 4);
        float xs[4] = {xv.x, xv.y, xv.z, xv.w};
        float s = xs[0] + xs[1] + xs[2] + xs[3];
        float s2 = xs[0] * xs[0] + xs[1] * xs[1] + xs[2] * xs[2] + xs[3] * xs[3];
#pragma unroll
        for (int m = 1; m < 64; m <<= 1) { s += __shfl_xor(s, m); s2 += __shfl_xor(s2, m); }
        float mean = s * (1.0f / 256.0f);
        float var = s2 * (1.0f / 256.0f) - mean * mean;
        float rstd = rsqrtf(fmaxf(var, 0.0f) + 1e-12f);
#pragma unroll
        for (int j = 0; j < 4; ++j) {
            int c = lane * 4 + j;
            float yv = (xs[j] - mean) * rstd * lng[c] + lnb[c];
            yL[r * 256 + c] = f2bf(yv);
        }
    }
    __syncthreads();

    // ---- phase 2: QKV projections (each wave owns a 64-col strip) ----
    const int nb = wave * 64;
    {
        f32x4 acc[4][4] = {};
        gemm49(yL, wqT, nb, lane, acc);
#pragma unroll
        for (int mt = 0; mt < 4; ++mt)
#pragma unroll
            for (int nt = 0; nt < 4; ++nt) {
                int col = nb + nt * 16 + (lane & 15);
                float bias = bq[col];
#pragma unroll
                for (int r = 0; r < 4; ++r) {
                    int row = mt * 16 + (lane >> 4) * 4 + r;
                    if (row < NTOK) qL[row * 256 + col] = f2bf((acc[mt][nt][r] + bias) * 0.125f);
                }
            }
    }
    {
        f32x4 acc[4][4] = {};
        gemm49(encL, wkT, nb, lane, acc);
#pragma unroll
        for (int mt = 0; mt < 4; ++mt)
#pragma unroll
            for (int nt = 0; nt < 4; ++nt) {
                int col = nb + nt * 16 + (lane & 15);
                float bias = bk[col];
#pragma unroll
                for (int r = 0; r < 4; ++r) {
                    int row = mt * 16 + (lane >> 4) * 4 + r;
                    if (row < NTOK) kL[row * 256 + col] = f2bf(acc[mt][nt][r] + bias);
                }
            }
    }
    {
        f32x4 acc[4][4] = {};
        gemm49(encL, wvT, nb, lane, acc);
#pragma unroll
        for (int mt = 0; mt < 4; ++mt)
#pragma unroll
            for (int nt = 0; nt < 4; ++nt) {
                int col = nb + nt * 16 + (lane & 15);
                float bias = bv[col];
#pragma unroll
                for (int r = 0; r < 4; ++r) {
                    int row = mt * 16 + (lane >> 4) * 4 + r;
                    if (row < NTOK) vT[col * 64 + row] = f2bf(acc[mt][nt][r] + bias); // [channel][token]
                }
            }
    }
    // zero vT pad tokens 49..63
    for (int idx = tid; idx < 256 * 15; idx += 256) {
        int col = idx / 15, r = 49 + idx - (idx / 15) * 15;
        vT[col * 64 + r] = 0;
    }
    __syncthreads();

    // ---- phase 3: S = q_h @ k_h^T + relpos bias (+ shift mask); wave = head ----
    {
        const int hh = wave;
        const int ar = lane & 15;
        const int kg = (lane >> 4) * 8;
        const bf16x8 z = zfrag();
        f32x4 sa[4][4] = {};
        for (int k0 = 0; k0 < 64; k0 += 32) {
            bf16x8 a[4], bb[4];
#pragma unroll
            for (int mt = 0; mt < 4; ++mt) {
                int row = mt * 16 + ar;
                a[mt] = (row < NTOK) ? *(const bf16x8*)(qL + row * 256 + hh * 64 + k0 + kg) : z;
            }
#pragma unroll
            for (int nt = 0; nt < 4; ++nt) {
                int col = nt * 16 + ar;
                bb[nt] = (col < NTOK) ? *(const bf16x8*)(kL + col * 256 + hh * 64 + k0 + kg) : z;
            }
#pragma unroll
            for (int mt = 0; mt < 4; ++mt)
#pragma unroll
                for (int nt = 0; nt < 4; ++nt)
                    sa[mt][nt] = __builtin_amdgcn_mfma_f32_16x16x32_bf16(a[mt], bb[nt], sa[mt][nt], 0, 0, 0);
        }
#pragma unroll
        for (int mt = 0; mt < 4; ++mt)
#pragma unroll
            for (int nt = 0; nt < 4; ++nt) {
                int j = nt * 16 + (lane & 15);
#pragma unroll
                for (int r = 0; r < 4; ++r) {
                    int i = mt * 16 + (lane >> 4) * 4 + r;
                    if (i < NTOK && j < NTOK) {
                        float v = sa[mt][nt][r];
                        int yi = i / 7, xi = i - yi * 7;
                        int yj = j / 7, xj = j - yj * 7;
                        int ridx = (yi - yj + 6) * 13 + (xi - xj + 6);
                        v += rpb[ridx * 4 + hh];
                        if (shift > 0 && label[i] != label[j]) v -= 100.0f;
                        S[hh * 2401 + i * 49 + j] = v;
                    }
                }
            }
    }
    __syncthreads();   // all q/k reads done; S complete

    // ---- phase 4: softmax rows (lane = row), write P bf16 with K-pad ----
    if (lane < NTOK) {
        float* Srow = S + wave * 2401 + lane * 49;
        float m = -1e30f;
        for (int j = 0; j < NTOK; ++j) m = fmaxf(m, Srow[j]);
        float sum = 0.f;
        for (int j = 0; j < NTOK; ++j) { float e = expf(Srow[j] - m); Srow[j] = e; sum += e; }
        float inv = 1.0f / sum;
        u16* Prow = P + wave * (NTOK * 64) + lane * 64;
        for (int j = 0; j < NTOK; ++j) Prow[j] = f2bf(Srow[j] * inv);
        for (int j = NTOK; j < 64; ++j) Prow[j] = 0;
    }
    __syncthreads();   // P complete before PV (cross-lane LDS dependency)

    // ---- phase 5: O_h = P_h @ V_h ; wave = head ----
    {
        const int hh = wave;
        const int ar = lane & 15;
        const int kg = (lane >> 4) * 8;
        const bf16x8 z = zfrag();
        f32x4 oa[4][4] = {};
        for (int k0 = 0; k0 < 64; k0 += 32) {
            bf16x8 a[4], bb[4];
#pragma unroll
            for (int mt = 0; mt < 4; ++mt) {
                int row = mt * 16 + ar;
                a[mt] = (row < NTOK) ? *(const bf16x8*)(P + hh * (NTOK * 64) + row * 64 + k0 + kg) : z;
            }
#pragma unroll
            for (int nt = 0; nt < 4; ++nt) {
                int col = nt * 16 + ar;
                bb[nt] = *(const bf16x8*)(vT + (hh * 64 + col) * 64 + k0 + kg);
            }
#pragma unroll
            for (int mt = 0; mt < 4; ++mt)
#pragma unroll
                for (int nt = 0; nt < 4; ++nt)
                    oa[mt][nt] = __builtin_amdgcn_mfma_f32_16x16x32_bf16(a[mt], bb[nt], oa[mt][nt], 0, 0, 0);
        }
#pragma unroll
        for (int mt = 0; mt < 4; ++mt)
#pragma unroll
            for (int nt = 0; nt < 4; ++nt) {
                int col = nt * 16 + (lane & 15);
#pragma unroll
                for (int r = 0; r < 4; ++r) {
                    int row = mt * 16 + (lane >> 4) * 4 + r;
                    if (row < NTOK) O[row * 256 + hh * 64 + col] = f2bf(oa[mt][nt][r]);
                }
            }
    }
    __syncthreads();   // O complete

    // ---- phase 6: dst = src + O @ Wp + bp (fp32 residual, scatter via t_idx) ----
    {
        f32x4 acc[4][4] = {};
        gemm49(O, wpT, nb, lane, acc);
#pragma unroll
        for (int mt = 0; mt < 4; ++mt)
#pragma unroll
            for (int nt = 0; nt < 4; ++nt) {
                int col = nb + nt * 16 + (lane & 15);
                float bias = bp[col];
#pragma unroll
                for (int r = 0; r < 4; ++r) {
                    int row = mt * 16 + (lane >> 4) * 4 + r;
                    if (row < NTOK) {
                        size_t off = (size_t)t_idx[row] * 256 + col;
                        dst[off] = src[off] + acc[mt][nt][r] + bias;
                    }
                }
            }
    }
}

// ---------------- fused MLP (in place): R = R + fc2(gelu(fc1(LN(R)))) ----------------
// grid = T_TOK/64, block = 256 (4 waves). Hidden looped in 4 chunks of 256.
__global__ __launch_bounds__(256) void k_mlp(
    float* R,
    const float* __restrict__ lng, const float* __restrict__ lnb,
    const u16* __restrict__ fc1T, const float* __restrict__ fc1b,
    const u16* __restrict__ fc2T, const float* __restrict__ fc2b)
{
    __shared__ __align__(16) u16 yL[64 * 256];
    __shared__ __align__(16) u16 hL[64 * 256];
    const int tid = threadIdx.x, lane = tid & 63, wave = tid >> 6;
    const size_t t0 = (size_t)blockIdx.x * 64;

    for (int r = wave; r < 64; r += 4) {
        const float4 xv = *(const float4*)(R + (t0 + r) * 256 + lane * 4);
        float xs[4] = {xv.x, xv.y, xv.z, xv.w};
        float s = xs[0] + xs[1] + xs[2] + xs[3];
        float s2 = xs[0] * xs[0] + xs[1] * xs[1] + xs[2] * xs[2] + xs[3] * xs[3];
#pragma unroll
        for (int m = 1; m < 64; m <<= 1) { s += __shfl_xor(s, m); s2 += __shfl_xor(s2, m); }
        float mean = s * (1.0f / 256.0f);
        float var = s2 * (1.0f / 256.0f) - mean * mean;
        float rstd = rsqrtf(fmaxf(var, 0.0f) + 1e-12f);
#pragma unroll
        for (int j = 0; j < 4; ++j) {
            int c = lane * 4 + j;
            float yv = (xs[j] - mean) * rstd * lng[c] + lnb[c];
            yL[r * 256 + c] = f2bf(yv);
        }
    }
    __syncthreads();

    const int nb = wave * 64;
    const int ar = lane & 15;
    const int kg = (lane >> 4) * 8;
    f32x4 acc2[4][4] = {};
    for (int ch = 0; ch < 4; ++ch) {
        // GEMM1: h_chunk = gelu(yL @ fc1[:, ch*256+...] + b1)
        f32x4 acc1[4][4] = {};
        for (int k0 = 0; k0 < 256; k0 += 32) {
            bf16x8 a[4], bb[4];
#pragma unroll
            for (int mt = 0; mt < 4; ++mt)
                a[mt] = *(const bf16x8*)(yL + (mt * 16 + ar) * 256 + k0 + kg);
#pragma unroll
            for (int nt = 0; nt < 4; ++nt) {
                int hidx = ch * 256 + nb + nt * 16 + ar;
                bb[nt] = *(const bf16x8*)(fc1T + (size_t)hidx * 256 + k0 + kg);
            }
#pragma unroll
            for (int mt = 0; mt < 4; ++mt)
#pragma unroll
                for (int nt = 0; nt < 4; ++nt)
                    acc1[mt][nt] = __builtin_amdgcn_mfma_f32_16x16x32_bf16(a[mt], bb[nt], acc1[mt][nt], 0, 0, 0);
        }
#pragma unroll
        for (int mt = 0; mt < 4; ++mt)
#pragma unroll
            for (int nt = 0; nt < 4; ++nt) {
                int lcol = nb + nt * 16 + (lane & 15);
                float bias = fc1b[ch * 256 + lcol];
#pragma unroll
                for (int r = 0; r < 4; ++r) {
                    int row = mt * 16 + (lane >> 4) * 4 + r;
                    float v = acc1[mt][nt][r] + bias;
                    v = 0.5f * v * (1.0f + erff(v * 0.70710678f));
                    hL[row * 256 + lcol] = f2bf(v);
                }
            }
        __syncthreads();
        // GEMM2: acc2 += h_chunk @ fc2[ch*256+..., :]
        for (int k0 = 0; k0 < 256; k0 += 32) {
            bf16x8 a[4], bb[4];
#pragma unroll
            for (int mt = 0; mt < 4; ++mt)
                a[mt] = *(const bf16x8*)(hL + (mt * 16 + ar) * 256 + k0 + kg);
#pragma unroll
            for (int nt = 0; nt < 4; ++nt) {
                int col = nb + nt * 16 + ar;
                bb[nt] = *(const bf16x8*)(fc2T + (size_t)col * 1024 + ch * 256 + k0 + kg);
            }
#pragma unroll
            for (int mt = 0; mt < 4; ++mt)
#pragma unroll
                for (int nt = 0; nt < 4; ++nt)
                    acc2[mt][nt] = __builtin_amdgcn_mfma_f32_16x16x32_bf16(a[mt], bb[nt], acc2[mt][nt], 0, 0, 0);
        }
        __syncthreads();
    }
#pragma unroll
    for (int mt = 0; mt < 4; ++mt)
#pragma unroll
        for (int nt = 0; nt < 4; ++nt) {
            int col = nb + nt * 16 + (lane & 15);
            float bias = fc2b[col];
#pragma unroll
            for (int r = 0; r < 4; ++r) {
                int row = mt * 16 + (lane >> 4) * 4 + r;
                size_t off = (t0 + row) * 256 + col;
                R[off] = acc2[mt][nt][r] + bias + R[off];
            }
        }
}

extern "C" void kernel_launch(void* const* d_in, const int* in_sizes, int n_in,
                              void* d_out, int out_size, void* d_ws, size_t ws_size,
                              hipStream_t stream) {
    (void)in_sizes; (void)n_in; (void)out_size; (void)ws_size;
    // setup_inputs() dict order (all float32):
    // 0 x, 1 enc, 2 self_mask(bool), 3 dec_enc_mask(bool, all False), 4 ln1_g, 5 ln1_b,
    // 6 ln2_g, 7 ln2_b, 8 ln3_g, 9 ln3_b, 10 wq1, 11 wk1, 12 wv1, 13 wp1, 14 bq1,
    // 15 bk1, 16 bv1, 17 bp1, 18 rpb1, 19 wq2, 20 wk2, 21 wv2, 22 wp2, 23 bq2,
    // 24 bk2, 25 bv2, 26 bp2, 27 rpb2, 28 fc1_w, 29 fc1_b, 30 fc2_w, 31 fc2_b
    // Workspace: transposed bf16 weights only (2 MB).
    u16* WTbase = (u16*)d_ws;
    u16* wT[8];
    for (int i = 0; i < 8; ++i) wT[i] = WTbase + (size_t)i * 65536;
    u16* fc1T = WTbase + (size_t)8 * 65536;                     // [1024][256]
    u16* fc2T = fc1T + 262144;                                  // [256][1024]

    const int wsrc[8] = {10, 11, 12, 13, 19, 20, 21, 22};
    for (int i = 0; i < 8; ++i)
        k_transpose<<<256, 256, 0, stream>>>((const float*)d_in[wsrc[i]], wT[i], 256, 256);
    k_transpose<<<1024, 256, 0, stream>>>((const float*)d_in[28], fc1T, 256, 1024);
    k_transpose<<<1024, 256, 0, stream>>>((const float*)d_in[30], fc2T, 1024, 256);

    float* R = (float*)d_out;   // fp32 residual stream lives in d_out

    // block 1 (shift=0): R = x + attn1(LN(x), enc)
    k_win_attn<<<4096, 256, 0, stream>>>((const float*)d_in[0], R, (const float*)d_in[1],
        (const float*)d_in[4], (const float*)d_in[5],
        wT[0], wT[1], wT[2], wT[3],
        (const float*)d_in[14], (const float*)d_in[15], (const float*)d_in[16], (const float*)d_in[17],
        (const float*)d_in[18], 0);
    // block 2 (shift=3, + shift mask): R += attn2(LN(R), enc)
    k_win_attn<<<4096, 256, 0, stream>>>(R, R, (const float*)d_in[1],
        (const float*)d_in[6], (const float*)d_in[7],
        wT[4], wT[5], wT[6], wT[7],
        (const float*)d_in[23], (const float*)d_in[24], (const float*)d_in[25], (const float*)d_in[26],
        (const float*)d_in[27], 3);
    // MLP + final residual, in place on R
    k_mlp<<<T_TOK / 64, 256, 0, stream>>>(R,
        (const float*)d_in[8], (const float*)d_in[9],
        fc1T, (const float*)d_in[29], fc2T, (const float*)d_in[31]);
}

// Round 4
// 2457.105 us; speedup vs baseline: 1.0170x; 1.0170x over previous
//
#include <hip/hip_runtime.h>

typedef unsigned short u16;
typedef __bf16 bf16x8 __attribute__((ext_vector_type(8)));
typedef float f32x4 __attribute__((ext_vector_type(4)));

#define T_TOK 200704   // 4*224*224
#define NTOK 49
#define SY 264         // padded stride for [49][256] token-major bf16 tiles
#define SV 72          // padded token-stride for vT [256 ch][72]
#define SP 72          // padded k-stride for P [49][72] per head

__device__ __forceinline__ u16 f2bf(float f) {
    union { float f; unsigned u; } v; v.f = f;
    return (u16)((v.u + 0x7FFFu + ((v.u >> 16) & 1u)) >> 16);
}
__device__ __forceinline__ bf16x8 zfrag() {
    bf16x8 z;
#pragma unroll
    for (int i = 0; i < 8; ++i) z[i] = (__bf16)0.0f;
    return z;
}

// ---------------- transpose fp32 (K x N) -> bf16 (N x K) ----------------
__global__ void k_transpose(const float* __restrict__ in, u16* __restrict__ out, int K, int N) {
    int idx = blockIdx.x * blockDim.x + threadIdx.x;
    if (idx >= K * N) return;
    int k = idx / N, n = idx - k * N;
    out[n * K + k] = f2bf(in[idx]);
}

// Half-height GEMM: rows [mtb*16, mtb*16+31] of out(49x256) = A(49x256) @ W,
// strip cols [nb, nb+63]. A in LDS row-major stride SY. WT bf16 global [n][k].
__device__ __forceinline__ void gemm49h(const u16* A, const u16* WT,
                                        int nb, int mtb, int lane, f32x4 acc[2][4]) {
    const int ar = lane & 15;
    const int kg = (lane >> 4) * 8;
    const bf16x8 z = zfrag();
    for (int k0 = 0; k0 < 256; k0 += 32) {
        bf16x8 a[2], bb[4];
#pragma unroll
        for (int m = 0; m < 2; ++m) {
            int row = (mtb + m) * 16 + ar;
            a[m] = (row < NTOK) ? *(const bf16x8*)(A + row * SY + k0 + kg) : z;
        }
#pragma unroll
        for (int nt = 0; nt < 4; ++nt) {
            int col = nb + nt * 16 + ar;
            bb[nt] = *(const bf16x8*)(WT + col * 256 + k0 + kg);
        }
#pragma unroll
        for (int m = 0; m < 2; ++m)
#pragma unroll
            for (int nt = 0; nt < 4; ++nt)
                acc[m][nt] = __builtin_amdgcn_mfma_f32_16x16x32_bf16(a[m], bb[nt], acc[m][nt], 0, 0, 0);
    }
}

// ---------------- fused windowed cross-attention block ----------------
// grid = 4096 (B*nW), block = 512 (8 waves: strip s=w&3, half hf=w>>2).
// dst = src + reverse(proj(attn(LN(src) windows, enc windows))). fp32 global I/O.
// src may alias dst (block 2 in-place): each block touches only its own tokens.
__global__ __launch_bounds__(512) void k_win_attn(
    const float* src, float* dst, const float* __restrict__ enc,
    const float* __restrict__ lng, const float* __restrict__ lnb,
    const u16* __restrict__ wqT, const u16* __restrict__ wkT,
    const u16* __restrict__ wvT, const u16* __restrict__ wpT,
    const float* __restrict__ bq, const float* __restrict__ bk,
    const float* __restrict__ bv, const float* __restrict__ bp,
    const float* __restrict__ rpb, int shift)
{
    __shared__ __align__(16) char smem[117248];
    u16* yL   = (u16*)(smem);                 // [49][264]; later P [4][49][72]
    u16* P    = (u16*)(smem);
    u16* encL = (u16*)(smem + 28224);         // [49][264]; later qL
    u16* qL   = (u16*)(smem + 28224);
    u16* kL   = (u16*)(smem + 54096);         // [49][264]; later O
    u16* O    = (u16*)(smem + 54096);
    u16* vT   = (u16*)(smem + 79968);         // [256][72] (channel-major, token-padded)
    int* t_idx = (int*)(smem + 116832);       // [49]
    int* label = (int*)(smem + 117028);       // [49]

    const int tid = threadIdx.x, lane = tid & 63;
    const int w = tid >> 6;
    const int s  = w & 3;        // col strip / head
    const int hf = w >> 2;       // row half
    const int mtb = hf * 2;      // m-tile base (2 tiles per wave)
    const int l15 = lane & 15, g = lane >> 4, kg = g * 8;

    const int wi = blockIdx.x;
    const int b  = wi >> 10;
    const int wl = wi & 1023;
    const int wh = wl >> 5, wwi = wl & 31;

    if (tid < NTOK) {
        int yi = tid / 7, xi = tid - yi * 7;
        int h = wh * 7 + yi + shift; if (h >= 224) h -= 224;
        int ww = wwi * 7 + xi + shift; if (ww >= 224) ww -= 224;
        t_idx[tid] = (b * 224 + h) * 224 + ww;
        int hp = wh * 7 + yi, wp = wwi * 7 + xi;   // rolled-frame coords
        int rh = (hp < 217) ? 0 : ((hp < 221) ? 1 : 2);
        int rw = (wp < 217) ? 0 : ((wp < 221) ? 1 : 2);
        label[tid] = rh * 3 + rw;
    }
    // zero vT pad tokens 49..71 (read range is 49..63; 64..71 never read)
    for (int idx = tid; idx < 256 * 23; idx += 512) {
        int ch = idx / 23, tk = 49 + (idx - ch * 23);
        vT[ch * SV + tk] = 0;
    }
    __syncthreads();

    // ---- phase 1: load enc window (fp32->bf16) -> encL; LN(src) -> yL ----
    for (int idx = tid; idx < NTOK * 32; idx += 512) {
        int r = idx >> 5, c8 = (idx & 31) << 3;
        const float* ep = enc + (size_t)t_idx[r] * 256 + c8;
        const float4 v0 = *(const float4*)(ep);
        const float4 v1 = *(const float4*)(ep + 4);
        u16* p = encL + r * SY + c8;
        p[0] = f2bf(v0.x); p[1] = f2bf(v0.y); p[2] = f2bf(v0.z); p[3] = f2bf(v0.w);
        p[4] = f2bf(v1.x); p[5] = f2bf(v1.y); p[6] = f2bf(v1.z); p[7] = f2bf(v1.w);
    }
    for (int r = w; r < NTOK; r += 8) {
        const float4 xv = *(const float4*)(src + (size_t)t_idx[r] * 256 + lane * 4);
        float xs[4] = {xv.x, xv.y, xv.z, xv.w};
        float sm = xs[0] + xs[1] + xs[2] + xs[3];
        float s2 = xs[0] * xs[0] + xs[1] * xs[1] + xs[2] * xs[2] + xs[3] * xs[3];
#pragma unroll
        for (int m = 1; m < 64; m <<= 1) { sm += __shfl_xor(sm, m); s2 += __shfl_xor(s2, m); }
        float mean = sm * (1.0f / 256.0f);
        float var = s2 * (1.0f / 256.0f) - mean * mean;
        float rstd = rsqrtf(fmaxf(var, 0.0f) + 1e-12f);
#pragma unroll
        for (int j = 0; j < 4; ++j) {
            int c = lane * 4 + j;
            float yv = (xs[j] - mean) * rstd * lng[c] + lnb[c];
            yL[r * SY + c] = f2bf(yv);
        }
    }
    __syncthreads();

    const int nb = s * 64;

    // ---- phase 2b/2c: K and V projections from encL ----
    {
        f32x4 acc[2][4] = {};
        gemm49h(encL, wkT, nb, mtb, lane, acc);
#pragma unroll
        for (int m = 0; m < 2; ++m)
#pragma unroll
            for (int nt = 0; nt < 4; ++nt) {
                int col = nb + nt * 16 + l15;
                float bias = bk[col];
#pragma unroll
                for (int r = 0; r < 4; ++r) {
                    int row = (mtb + m) * 16 + g * 4 + r;
                    if (row < NTOK) kL[row * SY + col] = f2bf(acc[m][nt][r] + bias);
                }
            }
    }
    {
        f32x4 acc[2][4] = {};
        gemm49h(encL, wvT, nb, mtb, lane, acc);
#pragma unroll
        for (int m = 0; m < 2; ++m)
#pragma unroll
            for (int nt = 0; nt < 4; ++nt) {
                int col = nb + nt * 16 + l15;
                float bias = bv[col];
#pragma unroll
                for (int r = 0; r < 4; ++r) {
                    int row = (mtb + m) * 16 + g * 4 + r;
                    if (row < NTOK) vT[col * SV + row] = f2bf(acc[m][nt][r] + bias);
                }
            }
    }
    __syncthreads();   // encL reads done

    // ---- phase 2a: Q projection from yL -> qL (overlays encL), scaled 1/8 ----
    {
        f32x4 acc[2][4] = {};
        gemm49h(yL, wqT, nb, mtb, lane, acc);
#pragma unroll
        for (int m = 0; m < 2; ++m)
#pragma unroll
            for (int nt = 0; nt < 4; ++nt) {
                int col = nb + nt * 16 + l15;
                float bias = bq[col];
#pragma unroll
                for (int r = 0; r < 4; ++r) {
                    int row = (mtb + m) * 16 + g * 4 + r;
                    if (row < NTOK) qL[row * SY + col] = f2bf((acc[m][nt][r] + bias) * 0.125f);
                }
            }
    }
    __syncthreads();   // qL/kL ready; yL reads done

    // ---- phase 3: S = q_h k_h^T + bias (+mask); softmax in registers -> P ----
    {
        const int h = s;
        const bf16x8 z = zfrag();
        f32x4 sa[2][4] = {};
        for (int k0 = 0; k0 < 64; k0 += 32) {
            bf16x8 a[2], bb[4];
#pragma unroll
            for (int m = 0; m < 2; ++m) {
                int row = (mtb + m) * 16 + l15;
                a[m] = (row < NTOK) ? *(const bf16x8*)(qL + row * SY + h * 64 + k0 + kg) : z;
            }
#pragma unroll
            for (int nt = 0; nt < 4; ++nt) {
                int col = nt * 16 + l15;
                bb[nt] = (col < NTOK) ? *(const bf16x8*)(kL + col * SY + h * 64 + k0 + kg) : z;
            }
#pragma unroll
            for (int m = 0; m < 2; ++m)
#pragma unroll
                for (int nt = 0; nt < 4; ++nt)
                    sa[m][nt] = __builtin_amdgcn_mfma_f32_16x16x32_bf16(a[m], bb[nt], sa[m][nt], 0, 0, 0);
        }
#pragma unroll
        for (int m = 0; m < 2; ++m) {
#pragma unroll
            for (int rr = 0; rr < 4; ++rr) {
                int i = (mtb + m) * 16 + g * 4 + rr;
                bool iv = (i < NTOK);
                int yi = iv ? (i / 7) : 0, xi = iv ? (i - (i / 7) * 7) : 0;
                int li = iv ? label[i] : 0;
                float v[4], mx = -1e30f;
#pragma unroll
                for (int nt = 0; nt < 4; ++nt) {
                    int j = nt * 16 + l15;
                    float t = -1e30f;
                    if (iv && j < NTOK) {
                        t = sa[m][nt][rr];
                        int yj = j / 7, xj = j - (j / 7) * 7;
                        t += rpb[((yi - yj + 6) * 13 + (xi - xj + 6)) * 4 + h];
                        if (shift > 0 && li != label[j]) t -= 100.0f;
                    }
                    v[nt] = t;
                    mx = fmaxf(mx, t);
                }
#pragma unroll
                for (int mk = 1; mk < 16; mk <<= 1) mx = fmaxf(mx, __shfl_xor(mx, mk));
                float sum = 0.f, e[4];
#pragma unroll
                for (int nt = 0; nt < 4; ++nt) {
                    e[nt] = (v[nt] > -1e29f) ? __expf(v[nt] - mx) : 0.0f;
                    sum += e[nt];
                }
#pragma unroll
                for (int mk = 1; mk < 16; mk <<= 1) sum += __shfl_xor(sum, mk);
                float inv = 1.0f / sum;
                if (iv) {
                    u16* Prow = P + h * (NTOK * SP) + i * SP;
#pragma unroll
                    for (int nt = 0; nt < 4; ++nt) Prow[nt * 16 + l15] = f2bf(e[nt] * inv);
                }
            }
        }
    }
    __syncthreads();   // P ready; kL reads done

    // ---- phase 5: O_h = P_h @ V_h -> O (overlays kL) ----
    {
        const int h = s;
        const bf16x8 z = zfrag();
        f32x4 oa[2][4] = {};
        for (int k0 = 0; k0 < 64; k0 += 32) {
            bf16x8 a[2], bb[4];
#pragma unroll
            for (int m = 0; m < 2; ++m) {
                int row = (mtb + m) * 16 + l15;
                a[m] = (row < NTOK) ? *(const bf16x8*)(P + h * (NTOK * SP) + row * SP + k0 + kg) : z;
            }
#pragma unroll
            for (int nt = 0; nt < 4; ++nt) {
                int ch = h * 64 + nt * 16 + l15;
                bb[nt] = *(const bf16x8*)(vT + ch * SV + k0 + kg);
            }
#pragma unroll
            for (int m = 0; m < 2; ++m)
#pragma unroll
                for (int nt = 0; nt < 4; ++nt)
                    oa[m][nt] = __builtin_amdgcn_mfma_f32_16x16x32_bf16(a[m], bb[nt], oa[m][nt], 0, 0, 0);
        }
#pragma unroll
        for (int m = 0; m < 2; ++m)
#pragma unroll
            for (int nt = 0; nt < 4; ++nt) {
                int col = h * 64 + nt * 16 + l15;
#pragma unroll
                for (int r = 0; r < 4; ++r) {
                    int row = (mtb + m) * 16 + g * 4 + r;
                    if (row < NTOK) O[row * SY + col] = f2bf(oa[m][nt][r]);
                }
            }
    }
    __syncthreads();   // O complete

    // ---- phase 6: dst = src + O @ Wp + bp ----
    {
        f32x4 acc[2][4] = {};
        gemm49h(O, wpT, nb, mtb, lane, acc);
#pragma unroll
        for (int m = 0; m < 2; ++m)
#pragma unroll
            for (int nt = 0; nt < 4; ++nt) {
                int col = nb + nt * 16 + l15;
                float bias = bp[col];
#pragma unroll
                for (int r = 0; r < 4; ++r) {
                    int row = (mtb + m) * 16 + g * 4 + r;
                    if (row < NTOK) {
                        size_t off = (size_t)t_idx[row] * 256 + col;
                        dst[off] = src[off] + acc[m][nt][r] + bias;
                    }
                }
            }
    }
}

// ---------------- fused MLP (in place): R = R + fc2(gelu(fc1(LN(R)))) ----------------
// grid = T_TOK/64, block = 256 (4 waves). Hidden looped in 4 chunks of 256.
#define SM 264
__global__ __launch_bounds__(256) void k_mlp(
    float* R,
    const float* __restrict__ lng, const float* __restrict__ lnb,
    const u16* __restrict__ fc1T, const float* __restrict__ fc1b,
    const u16* __restrict__ fc2T, const float* __restrict__ fc2b)
{
    __shared__ __align__(16) u16 yL[64 * SM];
    __shared__ __align__(16) u16 hL[64 * SM];
    const int tid = threadIdx.x, lane = tid & 63, wave = tid >> 6;
    const size_t t0 = (size_t)blockIdx.x * 64;

    for (int r = wave; r < 64; r += 4) {
        const float4 xv = *(const float4*)(R + (t0 + r) * 256 + lane * 4);
        float xs[4] = {xv.x, xv.y, xv.z, xv.w};
        float s = xs[0] + xs[1] + xs[2] + xs[3];
        float s2 = xs[0] * xs[0] + xs[1] * xs[1] + xs[2] * xs[2] + xs[3] * xs[3];
#pragma unroll
        for (int m = 1; m < 64; m <<= 1) { s += __shfl_xor(s, m); s2 += __shfl_xor(s2, m); }
        float mean = s * (1.0f / 256.0f);
        float var = s2 * (1.0f / 256.0f) - mean * mean;
        float rstd = rsqrtf(fmaxf(var, 0.0f) + 1e-12f);
#pragma unroll
        for (int j = 0; j < 4; ++j) {
            int c = lane * 4 + j;
            float yv = (xs[j] - mean) * rstd * lng[c] + lnb[c];
            yL[r * SM + c] = f2bf(yv);
        }
    }
    __syncthreads();

    const int nb = wave * 64;
    const int ar = lane & 15;
    const int kg = (lane >> 4) * 8;
    f32x4 acc2[4][4] = {};
    for (int ch = 0; ch < 4; ++ch) {
        f32x4 acc1[4][4] = {};
        for (int k0 = 0; k0 < 256; k0 += 32) {
            bf16x8 a[4], bb[4];
#pragma unroll
            for (int mt = 0; mt < 4; ++mt)
                a[mt] = *(const bf16x8*)(yL + (mt * 16 + ar) * SM + k0 + kg);
#pragma unroll
            for (int nt = 0; nt < 4; ++nt) {
                int hidx = ch * 256 + nb + nt * 16 + ar;
                bb[nt] = *(const bf16x8*)(fc1T + (size_t)hidx * 256 + k0 + kg);
            }
#pragma unroll
            for (int mt = 0; mt < 4; ++mt)
#pragma unroll
                for (int nt = 0; nt < 4; ++nt)
                    acc1[mt][nt] = __builtin_amdgcn_mfma_f32_16x16x32_bf16(a[mt], bb[nt], acc1[mt][nt], 0, 0, 0);
        }
#pragma unroll
        for (int mt = 0; mt < 4; ++mt)
#pragma unroll
            for (int nt = 0; nt < 4; ++nt) {
                int lcol = nb + nt * 16 + (lane & 15);
                float bias = fc1b[ch * 256 + lcol];
#pragma unroll
                for (int r = 0; r < 4; ++r) {
                    int row = mt * 16 + (lane >> 4) * 4 + r;
                    float v = acc1[mt][nt][r] + bias;
                    v = 0.5f * v * (1.0f + erff(v * 0.70710678f));
                    hL[row * SM + lcol] = f2bf(v);
                }
            }
        __syncthreads();
        for (int k0 = 0; k0 < 256; k0 += 32) {
            bf16x8 a[4], bb[4];
#pragma unroll
            for (int mt = 0; mt < 4; ++mt)
                a[mt] = *(const bf16x8*)(hL + (mt * 16 + ar) * SM + k0 + kg);
#pragma unroll
            for (int nt = 0; nt < 4; ++nt) {
                int col = nb + nt * 16 + ar;
                bb[nt] = *(const bf16x8*)(fc2T + (size_t)col * 1024 + ch * 256 + k0 + kg);
            }
#pragma unroll
            for (int mt = 0; mt < 4; ++mt)
#pragma unroll
                for (int nt = 0; nt < 4; ++nt)
                    acc2[mt][nt] = __builtin_amdgcn_mfma_f32_16x16x32_bf16(a[mt], bb[nt], acc2[mt][nt], 0, 0, 0);
        }
        __syncthreads();
    }
#pragma unroll
    for (int mt = 0; mt < 4; ++mt)
#pragma unroll
        for (int nt = 0; nt < 4; ++nt) {
            int col = nb + nt * 16 + (lane & 15);
            float bias = fc2b[col];
#pragma unroll
            for (int r = 0; r < 4; ++r) {
                int row = mt * 16 + (lane >> 4) * 4 + r;
                size_t off = (t0 + row) * 256 + col;
                R[off] = acc2[mt][nt][r] + bias + R[off];
            }
        }
}

extern "C" void kernel_launch(void* const* d_in, const int* in_sizes, int n_in,
                              void* d_out, int out_size, void* d_ws, size_t ws_size,
                              hipStream_t stream) {
    (void)in_sizes; (void)n_in; (void)out_size; (void)ws_size;
    // inputs (all float32): 0 x, 1 enc, 2 self_mask, 3 dec_enc_mask, 4 ln1_g, 5 ln1_b,
    // 6 ln2_g, 7 ln2_b, 8 ln3_g, 9 ln3_b, 10 wq1, 11 wk1, 12 wv1, 13 wp1, 14 bq1,
    // 15 bk1, 16 bv1, 17 bp1, 18 rpb1, 19 wq2, 20 wk2, 21 wv2, 22 wp2, 23 bq2,
    // 24 bk2, 25 bv2, 26 bp2, 27 rpb2, 28 fc1_w, 29 fc1_b, 30 fc2_w, 31 fc2_b
    u16* WTbase = (u16*)d_ws;
    u16* wT[8];
    for (int i = 0; i < 8; ++i) wT[i] = WTbase + (size_t)i * 65536;
    u16* fc1T = WTbase + (size_t)8 * 65536;                     // [1024][256]
    u16* fc2T = fc1T + 262144;                                  // [256][1024]

    const int wsrc[8] = {10, 11, 12, 13, 19, 20, 21, 22};
    for (int i = 0; i < 8; ++i)
        k_transpose<<<256, 256, 0, stream>>>((const float*)d_in[wsrc[i]], wT[i], 256, 256);
    k_transpose<<<1024, 256, 0, stream>>>((const float*)d_in[28], fc1T, 256, 1024);
    k_transpose<<<1024, 256, 0, stream>>>((const float*)d_in[30], fc2T, 1024, 256);

    float* R = (float*)d_out;   // fp32 residual stream lives in d_out

    // block 1 (shift=0): R = x + attn1(LN(x), enc)
    k_win_attn<<<4096, 512, 0, stream>>>((const float*)d_in[0], R, (const float*)d_in[1],
        (const float*)d_in[4], (const float*)d_in[5],
        wT[0], wT[1], wT[2], wT[3],
        (const float*)d_in[14], (const float*)d_in[15], (const float*)d_in[16], (const float*)d_in[17],
        (const float*)d_in[18], 0);
    // block 2 (shift=3, + shift mask): R += attn2(LN(R), enc)
    k_win_attn<<<4096, 512, 0, stream>>>(R, R, (const float*)d_in[1],
        (const float*)d_in[6], (const float*)d_in[7],
        wT[4], wT[5], wT[6], wT[7],
        (const float*)d_in[23], (const float*)d_in[24], (const float*)d_in[25], (const float*)d_in[26],
        (const float*)d_in[27], 3);
    // MLP + final residual, in place on R
    k_mlp<<<T_TOK / 64, 256, 0, stream>>>(R,
        (const float*)d_in[8], (const float*)d_in[9],
        fc1T, (const float*)d_in[29], fc2T, (const float*)d_in[31]);
}

// Round 5
// 2065.404 us; speedup vs baseline: 1.2099x; 1.1896x over previous
//
#include <hip/hip_runtime.h>

typedef unsigned short u16;
typedef __bf16 bf16x8 __attribute__((ext_vector_type(8)));
typedef float f32x4 __attribute__((ext_vector_type(4)));

#define T_TOK 200704   // 4*224*224
#define NTOK 49
#define SA 264         // stride (u16) for [49][256] tiles: yL/encL/O, qL, kL, vL
#define SP 72          // P per-head row stride (16B-aligned: 72*2=144)

__device__ __forceinline__ u16 f2bf(float f) {
    union { float f; unsigned u; } v; v.f = f;
    return (u16)((v.u + 0x7FFFu + ((v.u >> 16) & 1u)) >> 16);
}
__device__ __forceinline__ bf16x8 zfrag() {
    bf16x8 z;
#pragma unroll
    for (int i = 0; i < 8; ++i) z[i] = (__bf16)0.0f;
    return z;
}

// ---------------- transpose fp32 (K x N) -> bf16 (N x K) ----------------
__global__ void k_transpose(const float* __restrict__ in, u16* __restrict__ out, int K, int N) {
    int idx = blockIdx.x * blockDim.x + threadIdx.x;
    if (idx >= K * N) return;
    int k = idx / N, n = idx - k * N;
    out[n * K + k] = f2bf(in[idx]);
}

// Half-height GEMM: rows [mtb*16, mtb*16+31] of out(49x256) = A(49x256) @ W,
// strip cols [nb, nb+63]. A in LDS row-major stride SA. WT bf16 global [n][k].
__device__ __forceinline__ void gemm49h(const u16* A, const u16* WT,
                                        int nb, int mtb, int lane, f32x4 acc[2][4]) {
    const int ar = lane & 15;
    const int kg = (lane >> 4) * 8;
    const bf16x8 z = zfrag();
    for (int k0 = 0; k0 < 256; k0 += 32) {
        bf16x8 a[2], bb[4];
#pragma unroll
        for (int m = 0; m < 2; ++m) {
            int row = (mtb + m) * 16 + ar;
            a[m] = (row < NTOK) ? *(const bf16x8*)(A + row * SA + k0 + kg) : z;
        }
#pragma unroll
        for (int nt = 0; nt < 4; ++nt) {
            int col = nb + nt * 16 + ar;
            bb[nt] = *(const bf16x8*)(WT + col * 256 + k0 + kg);
        }
#pragma unroll
        for (int m = 0; m < 2; ++m)
#pragma unroll
            for (int nt = 0; nt < 4; ++nt)
                acc[m][nt] = __builtin_amdgcn_mfma_f32_16x16x32_bf16(a[m], bb[nt], acc[m][nt], 0, 0, 0);
    }
}

// ---------------- fused windowed cross-attention block ----------------
// grid = 4096 (B*nW), block = 512 (8 waves: strip/head s=w&3, row-half hf=w>>2).
// dst = src + reverse(proj(attn(LN(src) windows, enc windows))). fp32 global I/O.
// LDS cut to 80.4 KB -> 2 blocks/CU for cross-block latency hiding.
__global__ __launch_bounds__(512, 4) void k_win_attn(
    const float* src, float* dst, const float* __restrict__ enc,
    const float* __restrict__ lng, const float* __restrict__ lnb,
    const u16* __restrict__ wqT, const u16* __restrict__ wkT,
    const u16* __restrict__ wvT, const u16* __restrict__ wpT,
    const float* __restrict__ bq, const float* __restrict__ bk,
    const float* __restrict__ bv, const float* __restrict__ bp,
    const float* __restrict__ rpb, int shift)
{
    // A: [49][264] yL -> encL -> O        (25,872 B @ 0)
    // B: qL [49][264] -> P [4][49][72]    (28,224 B @ 25,872)
    // C: kL [49][264] -> vL [49][264]     (25,872 B @ 54,096)
    // idx/label                           (392 B  @ 79,968)
    __shared__ __align__(16) char smem[80384];
    u16* tA = (u16*)(smem);
    u16* tB = (u16*)(smem + 25872);
    u16* tC = (u16*)(smem + 54096);
    int* t_idx = (int*)(smem + 79968);
    int* label = (int*)(smem + 80164);

    const int tid = threadIdx.x, lane = tid & 63;
    const int w = tid >> 6;
    const int s  = w & 3;        // col strip / head
    const int hf = w >> 2;       // row half
    const int mtb = hf * 2;      // m-tile base
    const int l15 = lane & 15, g = lane >> 4, kg = g * 8;
    const int nb = s * 64;

    const int wi = blockIdx.x;
    const int b  = wi >> 10;
    const int wl = wi & 1023;
    const int wh = wl >> 5, wwi = wl & 31;

    if (tid < NTOK) {
        int yi = tid / 7, xi = tid - yi * 7;
        int h = wh * 7 + yi + shift; if (h >= 224) h -= 224;
        int ww = wwi * 7 + xi + shift; if (ww >= 224) ww -= 224;
        t_idx[tid] = (b * 224 + h) * 224 + ww;
        int hp = wh * 7 + yi, wp = wwi * 7 + xi;   // rolled-frame coords
        int rh = (hp < 217) ? 0 : ((hp < 221) ? 1 : 2);
        int rw = (wp < 217) ? 0 : ((wp < 221) ? 1 : 2);
        label[tid] = rh * 3 + rw;
    }
    __syncthreads();

    // ---- phase 1: LN(src) -> yL (A) ----
    for (int r = w; r < NTOK; r += 8) {
        const float4 xv = *(const float4*)(src + (size_t)t_idx[r] * 256 + lane * 4);
        float xs[4] = {xv.x, xv.y, xv.z, xv.w};
        float sm = xs[0] + xs[1] + xs[2] + xs[3];
        float s2 = xs[0] * xs[0] + xs[1] * xs[1] + xs[2] * xs[2] + xs[3] * xs[3];
#pragma unroll
        for (int m = 1; m < 64; m <<= 1) { sm += __shfl_xor(sm, m); s2 += __shfl_xor(s2, m); }
        float mean = sm * (1.0f / 256.0f);
        float var = s2 * (1.0f / 256.0f) - mean * mean;
        float rstd = rsqrtf(fmaxf(var, 0.0f) + 1e-12f);
#pragma unroll
        for (int j = 0; j < 4; ++j) {
            int c = lane * 4 + j;
            float yv = (xs[j] - mean) * rstd * lng[c] + lnb[c];
            tA[r * SA + c] = f2bf(yv);
        }
    }
    __syncthreads();

    // ---- phase 2: Q = (yL @ wq + bq) * scale -> qL (B) ----
    {
        f32x4 acc[2][4] = {};
        gemm49h(tA, wqT, nb, mtb, lane, acc);
#pragma unroll
        for (int m = 0; m < 2; ++m)
#pragma unroll
            for (int nt = 0; nt < 4; ++nt) {
                int col = nb + nt * 16 + l15;
                float bias = bq[col];
#pragma unroll
                for (int r = 0; r < 4; ++r) {
                    int row = (mtb + m) * 16 + g * 4 + r;
                    if (row < NTOK) tB[row * SA + col] = f2bf((acc[m][nt][r] + bias) * 0.125f);
                }
            }
    }
    __syncthreads();   // yL reads done; A will be overwritten

    // ---- phase 3: stage enc window (fp32->bf16) -> encL (A) ----
    for (int idx = tid; idx < NTOK * 32; idx += 512) {
        int r = idx >> 5, c8 = (idx & 31) << 3;
        const float* ep = enc + (size_t)t_idx[r] * 256 + c8;
        const float4 v0 = *(const float4*)(ep);
        const float4 v1 = *(const float4*)(ep + 4);
        u16* p = tA + r * SA + c8;
        p[0] = f2bf(v0.x); p[1] = f2bf(v0.y); p[2] = f2bf(v0.z); p[3] = f2bf(v0.w);
        p[4] = f2bf(v1.x); p[5] = f2bf(v1.y); p[6] = f2bf(v1.z); p[7] = f2bf(v1.w);
    }
    __syncthreads();

    // ---- phase 4: K = encL @ wk + bk -> kL (C) ----
    {
        f32x4 acc[2][4] = {};
        gemm49h(tA, wkT, nb, mtb, lane, acc);
#pragma unroll
        for (int m = 0; m < 2; ++m)
#pragma unroll
            for (int nt = 0; nt < 4; ++nt) {
                int col = nb + nt * 16 + l15;
                float bias = bk[col];
#pragma unroll
                for (int r = 0; r < 4; ++r) {
                    int row = (mtb + m) * 16 + g * 4 + r;
                    if (row < NTOK) tC[row * SA + col] = f2bf(acc[m][nt][r] + bias);
                }
            }
    }
    __syncthreads();   // kL ready

    // ---- phase 5a: V-gemm (regs) + QK^T + softmax (all in registers) ----
    f32x4 vacc[2][4] = {};
    gemm49h(tA, wvT, nb, mtb, lane, vacc);   // V strip, result stays in regs

    f32x4 sa[2][4] = {};
    {
        const int h = s;
        const bf16x8 z = zfrag();
        for (int k0 = 0; k0 < 64; k0 += 32) {
            bf16x8 a[2], bb[4];
#pragma unroll
            for (int m = 0; m < 2; ++m) {
                int row = (mtb + m) * 16 + l15;
                a[m] = (row < NTOK) ? *(const bf16x8*)(tB + row * SA + h * 64 + k0 + kg) : z;
            }
#pragma unroll
            for (int nt = 0; nt < 4; ++nt) {
                int col = nt * 16 + l15;
                bb[nt] = (col < NTOK) ? *(const bf16x8*)(tC + col * SA + h * 64 + k0 + kg) : z;
            }
#pragma unroll
            for (int m = 0; m < 2; ++m)
#pragma unroll
                for (int nt = 0; nt < 4; ++nt)
                    sa[m][nt] = __builtin_amdgcn_mfma_f32_16x16x32_bf16(a[m], bb[nt], sa[m][nt], 0, 0, 0);
        }
        // softmax per row, in place into sa (prob values)
#pragma unroll
        for (int m = 0; m < 2; ++m) {
#pragma unroll
            for (int rr = 0; rr < 4; ++rr) {
                int i = (mtb + m) * 16 + g * 4 + rr;
                bool iv = (i < NTOK);
                int yi = iv ? (i / 7) : 0, xi = iv ? (i - (i / 7) * 7) : 0;
                int li = iv ? label[i] : 0;
                float v[4], mx = -1e30f;
#pragma unroll
                for (int nt = 0; nt < 4; ++nt) {
                    int j = nt * 16 + l15;
                    float t = -1e30f;
                    if (iv && j < NTOK) {
                        t = sa[m][nt][rr];
                        int yj = j / 7, xj = j - (j / 7) * 7;
                        t += rpb[((yi - yj + 6) * 13 + (xi - xj + 6)) * 4 + h];
                        if (shift > 0 && li != label[j]) t -= 100.0f;
                    }
                    v[nt] = t;
                    mx = fmaxf(mx, t);
                }
#pragma unroll
                for (int mk = 1; mk < 16; mk <<= 1) mx = fmaxf(mx, __shfl_xor(mx, mk));
                float sum = 0.f, e[4];
#pragma unroll
                for (int nt = 0; nt < 4; ++nt) {
                    e[nt] = (v[nt] > -1e29f) ? __expf(v[nt] - mx) : 0.0f;
                    sum += e[nt];
                }
#pragma unroll
                for (int mk = 1; mk < 16; mk <<= 1) sum += __shfl_xor(sum, mk);
                float inv = 1.0f / sum;
#pragma unroll
                for (int nt = 0; nt < 4; ++nt) sa[m][nt][rr] = e[nt] * inv;
            }
        }
    }
    __syncthreads();   // all reads of qL(B), kL(C), encL(A) complete

    // ---- phase 5b: store P -> B [4][49][72]; store V -> vL (C) token-major ----
    {
        const int h = s;
#pragma unroll
        for (int m = 0; m < 2; ++m)
#pragma unroll
            for (int rr = 0; rr < 4; ++rr) {
                int i = (mtb + m) * 16 + g * 4 + rr;
                if (i < NTOK) {
                    u16* Prow = tB + h * (NTOK * SP) + i * SP;
#pragma unroll
                    for (int nt = 0; nt < 4; ++nt) Prow[nt * 16 + l15] = f2bf(sa[m][nt][rr]);
                }
            }
#pragma unroll
        for (int m = 0; m < 2; ++m)
#pragma unroll
            for (int nt = 0; nt < 4; ++nt) {
                int col = nb + nt * 16 + l15;
                float bias = bv[col];
#pragma unroll
                for (int r = 0; r < 4; ++r) {
                    int row = (mtb + m) * 16 + g * 4 + r;
                    if (row < NTOK) tC[row * SA + col] = f2bf(vacc[m][nt][r] + bias);
                }
            }
    }
    __syncthreads();   // P, vL ready

    // ---- phase 6: O_h = P_h @ V_h -> O (A) ----
    {
        const int h = s;
        const bf16x8 z = zfrag();
        f32x4 oa[2][4] = {};
        for (int k0 = 0; k0 < 64; k0 += 32) {
            bf16x8 a[2], bb[4];
#pragma unroll
            for (int m = 0; m < 2; ++m) {
                int row = (mtb + m) * 16 + l15;
                a[m] = (row < NTOK) ? *(const bf16x8*)(tB + h * (NTOK * SP) + row * SP + k0 + kg) : z;
            }
#pragma unroll
            for (int nt = 0; nt < 4; ++nt) {
                u16 tmp[8];
#pragma unroll
                for (int i = 0; i < 8; ++i) {
                    int tok = k0 + kg + i;
                    tmp[i] = (tok < NTOK) ? tC[tok * SA + h * 64 + nt * 16 + l15] : (u16)0;
                }
                bb[nt] = *(bf16x8*)tmp;
            }
#pragma unroll
            for (int m = 0; m < 2; ++m)
#pragma unroll
                for (int nt = 0; nt < 4; ++nt)
                    oa[m][nt] = __builtin_amdgcn_mfma_f32_16x16x32_bf16(a[m], bb[nt], oa[m][nt], 0, 0, 0);
        }
#pragma unroll
        for (int m = 0; m < 2; ++m)
#pragma unroll
            for (int nt = 0; nt < 4; ++nt) {
                int col = h * 64 + nt * 16 + l15;
#pragma unroll
                for (int r = 0; r < 4; ++r) {
                    int row = (mtb + m) * 16 + g * 4 + r;
                    if (row < NTOK) tA[row * SA + col] = f2bf(oa[m][nt][r]);
                }
            }
    }
    __syncthreads();   // O complete

    // ---- phase 7: dst = src + O @ Wp + bp ----
    {
        f32x4 acc[2][4] = {};
        gemm49h(tA, wpT, nb, mtb, lane, acc);
#pragma unroll
        for (int m = 0; m < 2; ++m)
#pragma unroll
            for (int nt = 0; nt < 4; ++nt) {
                int col = nb + nt * 16 + l15;
                float bias = bp[col];
#pragma unroll
                for (int r = 0; r < 4; ++r) {
                    int row = (mtb + m) * 16 + g * 4 + r;
                    if (row < NTOK) {
                        size_t off = (size_t)t_idx[row] * 256 + col;
                        dst[off] = src[off] + acc[m][nt][r] + bias;
                    }
                }
            }
    }
}

// ---------------- fused MLP (in place): R = R + fc2(gelu(fc1(LN(R)))) ----------------
#define SM 264
__global__ __launch_bounds__(256) void k_mlp(
    float* R,
    const float* __restrict__ lng, const float* __restrict__ lnb,
    const u16* __restrict__ fc1T, const float* __restrict__ fc1b,
    const u16* __restrict__ fc2T, const float* __restrict__ fc2b)
{
    __shared__ __align__(16) u16 yL[64 * SM];
    __shared__ __align__(16) u16 hL[64 * SM];
    const int tid = threadIdx.x, lane = tid & 63, wave = tid >> 6;
    const size_t t0 = (size_t)blockIdx.x * 64;

    for (int r = wave; r < 64; r += 4) {
        const float4 xv = *(const float4*)(R + (t0 + r) * 256 + lane * 4);
        float xs[4] = {xv.x, xv.y, xv.z, xv.w};
        float s = xs[0] + xs[1] + xs[2] + xs[3];
        float s2 = xs[0] * xs[0] + xs[1] * xs[1] + xs[2] * xs[2] + xs[3] * xs[3];
#pragma unroll
        for (int m = 1; m < 64; m <<= 1) { s += __shfl_xor(s, m); s2 += __shfl_xor(s2, m); }
        float mean = s * (1.0f / 256.0f);
        float var = s2 * (1.0f / 256.0f) - mean * mean;
        float rstd = rsqrtf(fmaxf(var, 0.0f) + 1e-12f);
#pragma unroll
        for (int j = 0; j < 4; ++j) {
            int c = lane * 4 + j;
            float yv = (xs[j] - mean) * rstd * lng[c] + lnb[c];
            yL[r * SM + c] = f2bf(yv);
        }
    }
    __syncthreads();

    const int nb = wave * 64;
    const int ar = lane & 15;
    const int kg = (lane >> 4) * 8;
    f32x4 acc2[4][4] = {};
    for (int ch = 0; ch < 4; ++ch) {
        f32x4 acc1[4][4] = {};
        for (int k0 = 0; k0 < 256; k0 += 32) {
            bf16x8 a[4], bb[4];
#pragma unroll
            for (int mt = 0; mt < 4; ++mt)
                a[mt] = *(const bf16x8*)(yL + (mt * 16 + ar) * SM + k0 + kg);
#pragma unroll
            for (int nt = 0; nt < 4; ++nt) {
                int hidx = ch * 256 + nb + nt * 16 + ar;
                bb[nt] = *(const bf16x8*)(fc1T + (size_t)hidx * 256 + k0 + kg);
            }
#pragma unroll
            for (int mt = 0; mt < 4; ++mt)
#pragma unroll
                for (int nt = 0; nt < 4; ++nt)
                    acc1[mt][nt] = __builtin_amdgcn_mfma_f32_16x16x32_bf16(a[mt], bb[nt], acc1[mt][nt], 0, 0, 0);
        }
#pragma unroll
        for (int mt = 0; mt < 4; ++mt)
#pragma unroll
            for (int nt = 0; nt < 4; ++nt) {
                int lcol = nb + nt * 16 + (lane & 15);
                float bias = fc1b[ch * 256 + lcol];
#pragma unroll
                for (int r = 0; r < 4; ++r) {
                    int row = mt * 16 + (lane >> 4) * 4 + r;
                    float v = acc1[mt][nt][r] + bias;
                    v = 0.5f * v * (1.0f + erff(v * 0.70710678f));
                    hL[row * SM + lcol] = f2bf(v);
                }
            }
        __syncthreads();
        for (int k0 = 0; k0 < 256; k0 += 32) {
            bf16x8 a[4], bb[4];
#pragma unroll
            for (int mt = 0; mt < 4; ++mt)
                a[mt] = *(const bf16x8*)(hL + (mt * 16 + ar) * SM + k0 + kg);
#pragma unroll
            for (int nt = 0; nt < 4; ++nt) {
                int col = nb + nt * 16 + ar;
                bb[nt] = *(const bf16x8*)(fc2T + (size_t)col * 1024 + ch * 256 + k0 + kg);
            }
#pragma unroll
            for (int mt = 0; mt < 4; ++mt)
#pragma unroll
                for (int nt = 0; nt < 4; ++nt)
                    acc2[mt][nt] = __builtin_amdgcn_mfma_f32_16x16x32_bf16(a[mt], bb[nt], acc2[mt][nt], 0, 0, 0);
        }
        __syncthreads();
    }
#pragma unroll
    for (int mt = 0; mt < 4; ++mt)
#pragma unroll
        for (int nt = 0; nt < 4; ++nt) {
            int col = nb + nt * 16 + (lane & 15);
            float bias = fc2b[col];
#pragma unroll
            for (int r = 0; r < 4; ++r) {
                int row = mt * 16 + (lane >> 4) * 4 + r;
                size_t off = (t0 + row) * 256 + col;
                R[off] = acc2[mt][nt][r] + bias + R[off];
            }
        }
}

extern "C" void kernel_launch(void* const* d_in, const int* in_sizes, int n_in,
                              void* d_out, int out_size, void* d_ws, size_t ws_size,
                              hipStream_t stream) {
    (void)in_sizes; (void)n_in; (void)out_size; (void)ws_size;
    u16* WTbase = (u16*)d_ws;
    u16* wT[8];
    for (int i = 0; i < 8; ++i) wT[i] = WTbase + (size_t)i * 65536;
    u16* fc1T = WTbase + (size_t)8 * 65536;                     // [1024][256]
    u16* fc2T = fc1T + 262144;                                  // [256][1024]

    const int wsrc[8] = {10, 11, 12, 13, 19, 20, 21, 22};
    for (int i = 0; i < 8; ++i)
        k_transpose<<<256, 256, 0, stream>>>((const float*)d_in[wsrc[i]], wT[i], 256, 256);
    k_transpose<<<1024, 256, 0, stream>>>((const float*)d_in[28], fc1T, 256, 1024);
    k_transpose<<<1024, 256, 0, stream>>>((const float*)d_in[30], fc2T, 1024, 256);

    float* R = (float*)d_out;   // fp32 residual stream lives in d_out

    // block 1 (shift=0): R = x + attn1(LN(x), enc)
    k_win_attn<<<4096, 512, 0, stream>>>((const float*)d_in[0], R, (const float*)d_in[1],
        (const float*)d_in[4], (const float*)d_in[5],
        wT[0], wT[1], wT[2], wT[3],
        (const float*)d_in[14], (const float*)d_in[15], (const float*)d_in[16], (const float*)d_in[17],
        (const float*)d_in[18], 0);
    // block 2 (shift=3, + shift mask): R += attn2(LN(R), enc)
    k_win_attn<<<4096, 512, 0, stream>>>(R, R, (const float*)d_in[1],
        (const float*)d_in[6], (const float*)d_in[7],
        wT[4], wT[5], wT[6], wT[7],
        (const float*)d_in[23], (const float*)d_in[24], (const float*)d_in[25], (const float*)d_in[26],
        (const float*)d_in[27], 3);
    // MLP + final residual, in place on R
    k_mlp<<<T_TOK / 64, 256, 0, stream>>>(R,
        (const float*)d_in[8], (const float*)d_in[9],
        fc1T, (const float*)d_in[29], fc2T, (const float*)d_in[31]);
}